// Round 1
// baseline (256.329 us; speedup 1.0000x reference)
//
#include <hip/hip_runtime.h>

// ---------------------------------------------------------------------------
// Q_DenseLayer: BN-fold int8 affine -> ReLU -> per-tensor 8b quant ->
// int8 3x3 conv (MFMA i32_16x16x64_i8) -> per-tensor 8b requant.
// Shapes: x[32,512,32,32] f32, W[128,512,3,3] f32, out y[32,128,32,32] + s_out.
// ---------------------------------------------------------------------------

typedef int v4i __attribute__((ext_vector_type(4)));

#define NB   32
#define CIN  512
#define HH   32
#define WW   32
#define COUT 128

// workspace byte offsets
#define WS_WINT  64        // 512 floats
#define WS_BINT  2176      // 512 floats
#define WS_WSC   4224      // 128 floats
#define WS_WQ    8192      // 589824 int8, layout [tap][cc(8)][co(128)][c64]
#define WS_X2    1048576   // 16777216 uint8, NHWC

__device__ __forceinline__ float wave_max(float m) {
#pragma unroll
    for (int off = 32; off; off >>= 1) m = fmaxf(m, __shfl_xor(m, off));
    return m;
}

// ---- kernel 1: BN fold, quantize per-channel affine, zero atomic scalars ----
__global__ __launch_bounds__(512) void k_prep_bn(
    const float* __restrict__ gamma, const float* __restrict__ beta,
    const float* __restrict__ mean,  const float* __restrict__ var,
    const float* __restrict__ asf, float* ws_f, unsigned* ws_u) {
    int t = threadIdx.x;  // 512
    float wbn = gamma[t] / sqrtf(var[t] + 1e-5f);
    float bbn = beta[t] - mean[t] * wbn;

    __shared__ float red[8];
    float m = wave_max(fabsf(wbn));
    if ((t & 63) == 0) red[t >> 6] = m;
    __syncthreads();
    float mall = red[0];
#pragma unroll
    for (int i = 1; i < 8; ++i) mall = fmaxf(mall, red[i]);

    float ws_bn = mall / 127.0f;
    float s_in  = asf[0];
    float bn_sf = ws_bn * s_in;
    float wint  = fminf(fmaxf(rintf(wbn / ws_bn), -128.f), 127.f);
    float bint  = rintf(bbn / bn_sf);
    ws_f[WS_WINT / 4 + t] = wint;
    ws_f[WS_BINT / 4 + t] = bint;
    if (t == 0) {
        ws_f[2] = bn_sf;
        ws_u[0] = 0u;  // absmax(x1) bits
        ws_u[1] = 0u;  // absmax(y) bits
    }
}

// ---- kernel 2: per-output-channel conv weight quant to int8 ----------------
// wq layout: [(tap*8 + c/64)*128 + co]*64 + (c%64)
__global__ __launch_bounds__(256) void k_prep_w(
    const float* __restrict__ cw, float* __restrict__ wsc,
    signed char* __restrict__ wq) {
    int co = blockIdx.x, t = threadIdx.x;
    const float* w = cw + (size_t)co * 4608;
    float m = 0.f;
    for (int j = t; j < 4608; j += 256) m = fmaxf(m, fabsf(w[j]));
    __shared__ float red[4];
    m = wave_max(m);
    if ((t & 63) == 0) red[t >> 6] = m;
    __syncthreads();
    float mall = fmaxf(fmaxf(red[0], red[1]), fmaxf(red[2], red[3]));
    float sc = mall / 127.0f;
    if (t == 0) wsc[co] = sc;
    for (int j = t; j < 4608; j += 256) {
        float q = fminf(fmaxf(rintf(w[j] / sc), -128.f), 127.f);
        int c = j / 9, tap = j - c * 9;  // layout [co][c][kh][kw]
        wq[(((size_t)tap * 8 + (c >> 6)) * 128 + co) * 64 + (c & 63)] = (signed char)q;
    }
}

// ---- kernel 3: global max of relu(bn-affine(x)) ---------------------------
__global__ __launch_bounds__(256) void k_xmax(
    const float4* __restrict__ x4, const float* __restrict__ asf,
    const float* __restrict__ ws_f, unsigned* __restrict__ amax) {
    float s_in  = asf[0];
    float bn_sf = ws_f[2];
    const float* wint = ws_f + WS_WINT / 4;
    const float* bint = ws_f + WS_BINT / 4;
    float m = 0.f;
    int stride = gridDim.x * blockDim.x;
    for (int i = blockIdx.x * blockDim.x + threadIdx.x; i < 4194304; i += stride) {
        float4 v = x4[i];
        int c = (i >> 8) & 511;  // 1024 elems (256 float4) per channel
        float wi = wint[c], bi = bint[c];
        float a = fmaxf(fmaf(v.x / s_in, wi, bi) * bn_sf, 0.f);
        float b = fmaxf(fmaf(v.y / s_in, wi, bi) * bn_sf, 0.f);
        float cc = fmaxf(fmaf(v.z / s_in, wi, bi) * bn_sf, 0.f);
        float d = fmaxf(fmaf(v.w / s_in, wi, bi) * bn_sf, 0.f);
        m = fmaxf(m, fmaxf(fmaxf(a, b), fmaxf(cc, d)));
    }
    __shared__ float red[4];
    m = wave_max(m);
    if ((threadIdx.x & 63) == 0) red[threadIdx.x >> 6] = m;
    __syncthreads();
    if (threadIdx.x == 0) {
        m = fmaxf(fmaxf(red[0], red[1]), fmaxf(red[2], red[3]));
        atomicMax(amax, __float_as_uint(m));
    }
}

// ---- kernel 4: quantize x to int8 NHWC (LDS byte-transpose) ---------------
// one block per (b, h): reads x[b, :, h, :] (NCHW), writes x2[b, h, :, c] (NHWC)
__global__ __launch_bounds__(256) void k_xquant(
    const float4* __restrict__ x4, const float* __restrict__ asf,
    const float* __restrict__ ws_f, const unsigned* __restrict__ amax,
    unsigned* __restrict__ x2u) {
    int bb = blockIdx.x >> 5, h = blockIdx.x & 31;
    float s_in  = asf[0];
    float bn_sf = ws_f[2];
    float s_act = __uint_as_float(amax[0]) / 127.0f;
    const float* wint = ws_f + WS_WINT / 4;
    const float* bint = ws_f + WS_BINT / 4;
    int t = threadIdx.x;

    __shared__ unsigned lds[512 * 9];  // row stride 9 dwords (8 data + 1 pad)

#pragma unroll
    for (int it = 0; it < 16; ++it) {
        int idx = it * 256 + t;
        int c = idx >> 3, f4 = idx & 7;
        float4 v = x4[((size_t)bb * 512 + c) * 256 + h * 8 + f4];
        float wi = wint[c], bi = bint[c];
        unsigned q0 = (unsigned)(int)fminf(rintf(fmaxf(fmaf(v.x / s_in, wi, bi) * bn_sf, 0.f) / s_act), 127.f);
        unsigned q1 = (unsigned)(int)fminf(rintf(fmaxf(fmaf(v.y / s_in, wi, bi) * bn_sf, 0.f) / s_act), 127.f);
        unsigned q2 = (unsigned)(int)fminf(rintf(fmaxf(fmaf(v.z / s_in, wi, bi) * bn_sf, 0.f) / s_act), 127.f);
        unsigned q3 = (unsigned)(int)fminf(rintf(fmaxf(fmaf(v.w / s_in, wi, bi) * bn_sf, 0.f) / s_act), 127.f);
        lds[c * 9 + f4] = q0 | (q1 << 8) | (q2 << 16) | (q3 << 24);
    }
    __syncthreads();

    // phase 2: gather 4 channel-dwords, 4x4 byte transpose, write NHWC
#pragma unroll
    for (int it2 = 0; it2 < 4; ++it2) {
        int cdw = (t & 31) + ((t >> 6) << 5);          // 0..127
        int wq4 = ((t >> 5) & 1) + (it2 << 1);         // 0..7
        unsigned u0 = lds[(4 * cdw + 0) * 9 + wq4];
        unsigned u1 = lds[(4 * cdw + 1) * 9 + wq4];
        unsigned u2 = lds[(4 * cdw + 2) * 9 + wq4];
        unsigned u3 = lds[(4 * cdw + 3) * 9 + wq4];
        unsigned* dst = x2u + ((size_t)(bb * 1024 + h * 32 + wq4 * 4)) * 128 + cdw;
#pragma unroll
        for (int k = 0; k < 4; ++k) {
            unsigned o = ((u0 >> (8 * k)) & 255) | (((u1 >> (8 * k)) & 255) << 8) |
                         (((u2 >> (8 * k)) & 255) << 16) | (((u3 >> (8 * k)) & 255) << 24);
            dst[(size_t)k * 128] = o;
        }
    }
}

// ---- kernel 5: int8 3x3 conv via MFMA, fused y-max ------------------------
// wave = 32 px (one half-row pair... 2 m-tiles of 16 w) x 64 co (4 n-tiles)
// grid: 512 blocks x 4 waves = 2048 waves = 1024 rows x 2 co-halves
__global__ __launch_bounds__(256) void k_conv(
    const unsigned char* __restrict__ x2, const signed char* __restrict__ wq,
    const float* __restrict__ wsc, const unsigned* __restrict__ amax,
    unsigned* __restrict__ amaxy, float* __restrict__ y) {
    int t = threadIdx.x;
    int lane = t & 63, wv = t >> 6;
    int gw = blockIdx.x * 4 + wv;     // 0..2047
    int ch = gw & 1;                  // co half
    int r  = gw >> 1;                 // row id 0..1023
    int bb = r >> 5, h = r & 31;
    int m = lane & 15, quad = lane >> 4;
    int co0 = ch * 64;

    v4i acc[2][4];
#pragma unroll
    for (int i = 0; i < 2; ++i)
#pragma unroll
        for (int j = 0; j < 4; ++j) acc[i][j] = (v4i){0, 0, 0, 0};

    const unsigned char* xb = x2 + (size_t)bb * (1024 * 512);

    for (int kh = 0; kh < 3; ++kh) {
        int h2 = h + kh - 1;
        bool hok = (unsigned)h2 < 32u;
        for (int kw = 0; kw < 3; ++kw) {
            int tap = kh * 3 + kw;
            int wa = m + kw - 1, wb2 = wa + 16;
            bool aok = hok && ((unsigned)wa < 32u);
            bool bok = hok && ((unsigned)wb2 < 32u);
            const v4i* pa = (const v4i*)(xb + ((h2 * 32 + wa) * 512 + quad * 16));
            const v4i* pb = (const v4i*)(xb + ((h2 * 32 + wb2) * 512 + quad * 16));
            const v4i* pw = (const v4i*)(wq + (size_t)tap * 8 * 128 * 64 + (co0 + m) * 64 + quad * 16);
#pragma unroll
            for (int cc = 0; cc < 8; ++cc) {
                v4i a0 = (v4i){0, 0, 0, 0}, a1 = (v4i){0, 0, 0, 0};
                if (aok) a0 = pa[cc * 4];   // 64-byte c-chunk step
                if (bok) a1 = pb[cc * 4];
#pragma unroll
                for (int nt = 0; nt < 4; ++nt) {
                    v4i bf = pw[cc * 512 + nt * 64];  // cc step 8KB, nt step 1KB (in 16B units)
                    acc[0][nt] = __builtin_amdgcn_mfma_i32_16x16x64_i8(a0, bf, acc[0][nt], 0, 0, 0);
                    acc[1][nt] = __builtin_amdgcn_mfma_i32_16x16x64_i8(a1, bf, acc[1][nt], 0, 0, 0);
                }
            }
        }
    }

    // epilogue: y = y_int * (s_act * ws_c[co]); C layout: col(lane&15)=co, row(quad*4+reg)=w
    float s_act = __uint_as_float(amax[0]) / 127.0f;
    float mx = 0.f;
#pragma unroll
    for (int nt = 0; nt < 4; ++nt) {
        int co = co0 + nt * 16 + m;
        float sf = s_act * wsc[co];
        float* yb = y + ((size_t)(bb * 128 + co)) * 1024 + h * 32;
#pragma unroll
        for (int rr = 0; rr < 4; ++rr) {
            int w = quad * 4 + rr;
            float v0 = (float)acc[0][nt][rr] * sf;
            float v1 = (float)acc[1][nt][rr] * sf;
            yb[w] = v0;
            yb[w + 16] = v1;
            mx = fmaxf(mx, fmaxf(fabsf(v0), fabsf(v1)));
        }
    }
    mx = wave_max(mx);
    if (lane == 0) atomicMax(amaxy, __float_as_uint(mx));
}

// ---- kernel 6: final requant in place + write s_out -----------------------
__global__ __launch_bounds__(256) void k_yquant(float* __restrict__ yout,
                                                const unsigned* __restrict__ ws_u) {
    float s_out = __uint_as_float(ws_u[1]) / 127.0f;
    float4* y4 = (float4*)yout;
    int stride = gridDim.x * blockDim.x;
    for (int i = blockIdx.x * blockDim.x + threadIdx.x; i < 1048576; i += stride) {
        float4 v = y4[i];
        v.x = fminf(fmaxf(rintf(v.x / s_out), -128.f), 127.f) * s_out;
        v.y = fminf(fmaxf(rintf(v.y / s_out), -128.f), 127.f) * s_out;
        v.z = fminf(fmaxf(rintf(v.z / s_out), -128.f), 127.f) * s_out;
        v.w = fminf(fmaxf(rintf(v.w / s_out), -128.f), 127.f) * s_out;
        y4[i] = v;
    }
    if (blockIdx.x == 0 && threadIdx.x == 0) yout[4194304] = s_out;
}

extern "C" void kernel_launch(void* const* d_in, const int* in_sizes, int n_in,
                              void* d_out, int out_size, void* d_ws, size_t ws_size,
                              hipStream_t stream) {
    const float* x     = (const float*)d_in[0];
    const float* asf   = (const float*)d_in[1];
    const float* gamma = (const float*)d_in[2];
    const float* beta  = (const float*)d_in[3];
    const float* mean  = (const float*)d_in[4];
    const float* var   = (const float*)d_in[5];
    const float* cw    = (const float*)d_in[6];

    float*    ws_f = (float*)d_ws;
    unsigned* ws_u = (unsigned*)d_ws;
    signed char*   wq = (signed char*)d_ws + WS_WQ;
    unsigned char* x2 = (unsigned char*)d_ws + WS_X2;
    float* y = (float*)d_out;

    k_prep_bn<<<1, 512, 0, stream>>>(gamma, beta, mean, var, asf, ws_f, ws_u);
    k_prep_w<<<128, 256, 0, stream>>>(cw, ws_f + WS_WSC / 4, wq);
    k_xmax<<<2048, 256, 0, stream>>>((const float4*)x, asf, ws_f, ws_u);
    k_xquant<<<1024, 256, 0, stream>>>((const float4*)x, asf, ws_f, ws_u, (unsigned*)x2);
    k_conv<<<512, 256, 0, stream>>>(x2, wq, ws_f + WS_WSC / 4, ws_u, ws_u + 1, y);
    k_yquant<<<1024, 256, 0, stream>>>(y, ws_u);
}